// Round 1
// baseline (641.617 us; speedup 1.0000x reference)
//
#include <hip/hip_runtime.h>

#define N_NODES 100000
#define F_IN 256
#define F_OUT 128

static constexpr int SCAN_BLOCKS = (N_NODES + 255) / 256;  // 391

// ---------------- GEMM: transformed[n][o] = sum_f x[n][f]*W[o][f] + b[o] ---
// 64-node x 128-out tile per block, 256 threads, 8x4 accumulators/thread.
__global__ __launch_bounds__(256) void gemm_kernel(
    const float* __restrict__ x, const float* __restrict__ W,
    const float* __restrict__ b, float* __restrict__ out) {
  __shared__ float As[64 * 36];   // pad 36 keeps 16B alignment (36*4=144, %16==0)
  __shared__ float Bs[128 * 36];
  const int tid = threadIdx.x;
  const int nb = blockIdx.x * 64;
  const int tm = tid >> 5;   // 0..7  -> node group of 8
  const int tn = tid & 31;   // 0..31 -> out col base
  float acc[8][4];
#pragma unroll
  for (int i = 0; i < 8; ++i)
#pragma unroll
    for (int j = 0; j < 4; ++j) acc[i][j] = 0.f;

  for (int kb = 0; kb < F_IN; kb += 32) {
#pragma unroll
    for (int i = 0; i < 2; ++i) {   // stage A: 64x32 floats, float4 loads
      int q = tid + 256 * i;        // 0..511
      int m = q >> 3, k4 = q & 7;
      int node = nb + m;
      float4 v = make_float4(0.f, 0.f, 0.f, 0.f);
      if (node < N_NODES) v = *(const float4*)(x + node * F_IN + kb + k4 * 4);
      *(float4*)(As + m * 36 + k4 * 4) = v;
    }
#pragma unroll
    for (int i = 0; i < 4; ++i) {   // stage B: 128x32 floats
      int q = tid + 256 * i;        // 0..1023
      int o = q >> 3, k4 = q & 7;
      float4 v = *(const float4*)(W + o * F_IN + kb + k4 * 4);
      *(float4*)(Bs + o * 36 + k4 * 4) = v;
    }
    __syncthreads();
#pragma unroll
    for (int k4 = 0; k4 < 8; ++k4) {
      float4 bf[4], af[8];
#pragma unroll
      for (int j = 0; j < 4; ++j)
        bf[j] = *(const float4*)(Bs + (tn + 32 * j) * 36 + k4 * 4);
#pragma unroll
      for (int i = 0; i < 8; ++i)
        af[i] = *(const float4*)(As + (tm * 8 + i) * 36 + k4 * 4);
#pragma unroll
      for (int i = 0; i < 8; ++i)
#pragma unroll
        for (int j = 0; j < 4; ++j) {
          acc[i][j] = fmaf(af[i].x, bf[j].x, acc[i][j]);
          acc[i][j] = fmaf(af[i].y, bf[j].y, acc[i][j]);
          acc[i][j] = fmaf(af[i].z, bf[j].z, acc[i][j]);
          acc[i][j] = fmaf(af[i].w, bf[j].w, acc[i][j]);
        }
    }
    __syncthreads();
  }
#pragma unroll
  for (int j = 0; j < 4; ++j) {
    float bias = b[tn + 32 * j];
#pragma unroll
    for (int i = 0; i < 8; ++i) {
      int node = nb + tm * 8 + i;
      if (node < N_NODES) out[node * F_OUT + tn + 32 * j] = acc[i][j] + bias;
    }
  }
}

// ---------------- CSR build ------------------------------------------------
__global__ void hist_kernel(const int* __restrict__ rows, int* __restrict__ counts,
                            int E) {
  int i = blockIdx.x * blockDim.x + threadIdx.x;
  if (i < E) atomicAdd(&counts[rows[i]], 1);
}

// exclusive scan, step 1: per-256 block scan
__global__ __launch_bounds__(256) void scan1_kernel(const int* __restrict__ counts,
                                                    int* __restrict__ offsets,
                                                    int* __restrict__ blockSums) {
  __shared__ int s[256];
  int i = blockIdx.x * 256 + threadIdx.x;
  int v = (i < N_NODES) ? counts[i] : 0;
  s[threadIdx.x] = v;
  __syncthreads();
  for (int off = 1; off < 256; off <<= 1) {
    int t = (threadIdx.x >= off) ? s[threadIdx.x - off] : 0;
    __syncthreads();
    s[threadIdx.x] += t;
    __syncthreads();
  }
  if (i < N_NODES) offsets[i] = s[threadIdx.x] - v;  // exclusive
  if (threadIdx.x == 255) blockSums[blockIdx.x] = s[255];
}

// step 2: scan the 391 block sums in a single 512-thread block
__global__ __launch_bounds__(512) void scan2_kernel(int* __restrict__ blockSums,
                                                    int nb) {
  __shared__ int s[512];
  int v = ((int)threadIdx.x < nb) ? blockSums[threadIdx.x] : 0;
  s[threadIdx.x] = v;
  __syncthreads();
  for (int off = 1; off < 512; off <<= 1) {
    int t = (threadIdx.x >= off) ? s[threadIdx.x - off] : 0;
    __syncthreads();
    s[threadIdx.x] += t;
    __syncthreads();
  }
  if ((int)threadIdx.x < nb) blockSums[threadIdx.x] = s[threadIdx.x] - v;
}

// step 3: add block offsets; init cursor
__global__ __launch_bounds__(256) void scan3_kernel(int* __restrict__ offsets,
                                                    const int* __restrict__ blockSums,
                                                    int* __restrict__ cursor) {
  int i = blockIdx.x * 256 + threadIdx.x;
  if (i < N_NODES) {
    int o = offsets[i] + blockSums[blockIdx.x];
    offsets[i] = o;
    cursor[i] = o;
  }
}

__global__ void fill_kernel(const int* __restrict__ rows, int* __restrict__ cursor,
                            int* __restrict__ perm, int E) {
  int i = blockIdx.x * blockDim.x + threadIdx.x;
  if (i < E) {
    int p = atomicAdd(&cursor[rows[i]], 1);
    perm[p] = i;
  }
}

// ---------------- SpMM: one wave per output row ----------------------------
// lane l accumulates out cols (2l, 2l+1) as float2; metadata for up to 64
// edges loaded cooperatively then broadcast via shfl -> 16-deep independent
// gather loads per chunk.
__global__ __launch_bounds__(256) void spmm_kernel(
    const float* __restrict__ transformed, const int* __restrict__ perm,
    const int* __restrict__ cols, const float* __restrict__ vals,
    const int* __restrict__ offsets, const int* __restrict__ counts,
    float* __restrict__ out) {
  int wave = (blockIdx.x * 256 + threadIdx.x) >> 6;
  int lane = threadIdx.x & 63;
  if (wave >= N_NODES) return;
  int row = wave;
  int start = offsets[row];
  int n = counts[row];
  float2 acc = make_float2(0.f, 0.f);
  const float2* __restrict__ t2 = (const float2*)transformed;
  for (int base = 0; base < n; base += 64) {
    int m = n - base;
    if (m > 64) m = 64;
    int c = 0;
    float v = 0.f;
    if (lane < m) {
      int e = perm[start + base + lane];
      c = cols[e];
      v = vals[e];
    }
    for (int j = 0; j < m; ++j) {
      int cj = __shfl(c, j, 64);
      float vj = __shfl(v, j, 64);
      float2 t = t2[(size_t)cj * 64 + lane];
      acc.x = fmaf(vj, t.x, acc.x);
      acc.y = fmaf(vj, t.y, acc.y);
    }
  }
  ((float2*)out)[(size_t)row * 64 + lane] = acc;
}

extern "C" void kernel_launch(void* const* d_in, const int* in_sizes, int n_in,
                              void* d_out, int out_size, void* d_ws, size_t ws_size,
                              hipStream_t stream) {
  const float* x    = (const float*)d_in[0];
  const int*   rows = (const int*)d_in[1];
  const int*   cols = (const int*)d_in[2];
  const float* vals = (const float*)d_in[3];
  const float* W    = (const float*)d_in[4];
  const float* b    = (const float*)d_in[5];
  float* out = (float*)d_out;
  const int E = in_sizes[1];

  // workspace layout (4-byte units): transformed | counts | offsets | cursor | blockSums | perm
  float* transformed = (float*)d_ws;
  int* counts    = (int*)(transformed + (size_t)N_NODES * F_OUT);
  int* offsets   = counts + N_NODES;
  int* cursor    = offsets + N_NODES;
  int* blockSums = cursor + N_NODES;
  int* perm      = blockSums + 512;

  hipMemsetAsync(counts, 0, N_NODES * sizeof(int), stream);

  gemm_kernel<<<(N_NODES + 63) / 64, 256, 0, stream>>>(x, W, b, transformed);
  hist_kernel<<<(E + 255) / 256, 256, 0, stream>>>(rows, counts, E);
  scan1_kernel<<<SCAN_BLOCKS, 256, 0, stream>>>(counts, offsets, blockSums);
  scan2_kernel<<<1, 512, 0, stream>>>(blockSums, SCAN_BLOCKS);
  scan3_kernel<<<SCAN_BLOCKS, 256, 0, stream>>>(offsets, blockSums, cursor);
  fill_kernel<<<(E + 255) / 256, 256, 0, stream>>>(rows, cursor, perm, E);
  spmm_kernel<<<(N_NODES + 3) / 4, 256, 0, stream>>>(transformed, perm, cols, vals,
                                                     offsets, counts, out);
}

// Round 2
// 502.428 us; speedup vs baseline: 1.2770x; 1.2770x over previous
//
#include <hip/hip_runtime.h>

#define N_NODES 100000
#define F_IN 256
#define F_OUT 128

static constexpr int SCAN_BLOCKS = (N_NODES + 255) / 256;  // 391

typedef __attribute__((ext_vector_type(8))) short bf16x8;
typedef __attribute__((ext_vector_type(4))) float f32x4;

__device__ inline unsigned short f2bf(float f) {  // RNE fp32->bf16
  unsigned u = __builtin_bit_cast(unsigned, f);
  u += 0x7fffu + ((u >> 16) & 1u);
  return (unsigned short)(u >> 16);
}

// ---------------- GEMM (bf16 MFMA): transformed[n][o] = x[n][:]·W[o][:] + b[o]
// 128x128 tile per block, BK=64, 256 threads = 4 waves in 2x2, 4x4 16x16 frags.
__global__ __launch_bounds__(256) void gemm_kernel(
    const float* __restrict__ x, const float* __restrict__ W,
    const float* __restrict__ b, unsigned short* __restrict__ tout) {
  __shared__ unsigned short As[128][72];  // pad 64->72: 2-way max on frag reads
  __shared__ unsigned short Bs[128][72];
  const int tid = threadIdx.x;
  const int wave = tid >> 6, lane = tid & 63;
  const int quad = lane >> 4, l16 = lane & 15;
  const int mw = (wave >> 1) * 64, nw = (wave & 1) * 64;
  const int blockM = blockIdx.x * 128;

  f32x4 acc[4][4];
#pragma unroll
  for (int i = 0; i < 4; ++i)
#pragma unroll
    for (int j = 0; j < 4; ++j) acc[i][j] = (f32x4){0.f, 0.f, 0.f, 0.f};

  const int row_s = tid >> 4;  // 0..15, +i*16
  const int c4 = tid & 15;     // float4 index within 64-col K-slab

  for (int kb = 0; kb < F_IN; kb += 64) {
#pragma unroll
    for (int i = 0; i < 8; ++i) {  // stage A: 128 rows x 64 cols, fp32->bf16
      int r = row_s + i * 16;
      int node = blockM + r;
      float4 v = make_float4(0.f, 0.f, 0.f, 0.f);
      if (node < N_NODES) v = *(const float4*)(x + (size_t)node * F_IN + kb + c4 * 4);
      unsigned short* p = &As[r][c4 * 4];
      p[0] = f2bf(v.x); p[1] = f2bf(v.y); p[2] = f2bf(v.z); p[3] = f2bf(v.w);
    }
#pragma unroll
    for (int i = 0; i < 8; ++i) {  // stage B = W (128 x 256 full)
      int r = row_s + i * 16;
      float4 v = *(const float4*)(W + (size_t)r * F_IN + kb + c4 * 4);
      unsigned short* p = &Bs[r][c4 * 4];
      p[0] = f2bf(v.x); p[1] = f2bf(v.y); p[2] = f2bf(v.z); p[3] = f2bf(v.w);
    }
    __syncthreads();
#pragma unroll
    for (int ks = 0; ks < 2; ++ks) {
      bf16x8 a[4], bb[4];
#pragma unroll
      for (int t = 0; t < 4; ++t)
        a[t] = *(const bf16x8*)&As[mw + t * 16 + l16][ks * 32 + quad * 8];
#pragma unroll
      for (int t = 0; t < 4; ++t)
        bb[t] = *(const bf16x8*)&Bs[nw + t * 16 + l16][ks * 32 + quad * 8];
#pragma unroll
      for (int i = 0; i < 4; ++i)
#pragma unroll
        for (int j = 0; j < 4; ++j)
          acc[i][j] = __builtin_amdgcn_mfma_f32_16x16x32_bf16(a[i], bb[j], acc[i][j], 0, 0, 0);
    }
    __syncthreads();
  }
  // epilogue: C/D layout col=lane&15, row=quad*4+reg; + bias, cvt bf16
#pragma unroll
  for (int i = 0; i < 4; ++i) {
#pragma unroll
    for (int j = 0; j < 4; ++j) {
      int o = nw + j * 16 + l16;
      float bias = b[o];
#pragma unroll
      for (int r = 0; r < 4; ++r) {
        int node = blockM + mw + i * 16 + quad * 4 + r;
        if (node < N_NODES)
          tout[(size_t)node * F_OUT + o] = f2bf(acc[i][j][r] + bias);
      }
    }
  }
}

// ---------------- CSR build ------------------------------------------------
__global__ void hist_kernel(const int* __restrict__ rows, int* __restrict__ counts,
                            int E) {
  int i = blockIdx.x * blockDim.x + threadIdx.x;
  if (i < E) atomicAdd(&counts[rows[i]], 1);
}

__global__ __launch_bounds__(256) void scan1_kernel(const int* __restrict__ counts,
                                                    int* __restrict__ offsets,
                                                    int* __restrict__ blockSums) {
  __shared__ int s[256];
  int i = blockIdx.x * 256 + threadIdx.x;
  int v = (i < N_NODES) ? counts[i] : 0;
  s[threadIdx.x] = v;
  __syncthreads();
  for (int off = 1; off < 256; off <<= 1) {
    int t = (threadIdx.x >= off) ? s[threadIdx.x - off] : 0;
    __syncthreads();
    s[threadIdx.x] += t;
    __syncthreads();
  }
  if (i < N_NODES) offsets[i] = s[threadIdx.x] - v;  // exclusive
  if (threadIdx.x == 255) blockSums[blockIdx.x] = s[255];
}

__global__ __launch_bounds__(512) void scan2_kernel(int* __restrict__ blockSums,
                                                    int nb) {
  __shared__ int s[512];
  int v = ((int)threadIdx.x < nb) ? blockSums[threadIdx.x] : 0;
  s[threadIdx.x] = v;
  __syncthreads();
  for (int off = 1; off < 512; off <<= 1) {
    int t = (threadIdx.x >= off) ? s[threadIdx.x - off] : 0;
    __syncthreads();
    s[threadIdx.x] += t;
    __syncthreads();
  }
  if ((int)threadIdx.x < nb) blockSums[threadIdx.x] = s[threadIdx.x] - v;
}

__global__ __launch_bounds__(256) void scan3_kernel(int* __restrict__ offsets,
                                                    const int* __restrict__ blockSums,
                                                    int* __restrict__ cursor) {
  int i = blockIdx.x * 256 + threadIdx.x;
  if (i < N_NODES) {
    int o = offsets[i] + blockSums[blockIdx.x];
    offsets[i] = o;
    cursor[i] = o;
  }
}

// fill: write permuted (col, val) pairs directly — spmm reads them coalesced.
__global__ void fill_kernel(const int* __restrict__ rows, const int* __restrict__ cols,
                            const float* __restrict__ vals, int* __restrict__ cursor,
                            int2* __restrict__ edata, int E) {
  int i = blockIdx.x * blockDim.x + threadIdx.x;
  if (i < E) {
    int p = atomicAdd(&cursor[rows[i]], 1);
    edata[p] = make_int2(cols[i], __float_as_int(vals[i]));
  }
}

// ---------------- SpMM: one wave per row, bf16 gathers ---------------------
__global__ __launch_bounds__(256) void spmm_kernel(
    const unsigned short* __restrict__ tb, const int2* __restrict__ edata,
    const int* __restrict__ offsets, const int* __restrict__ counts,
    float* __restrict__ out) {
  int wave = (blockIdx.x * 256 + threadIdx.x) >> 6;
  int lane = threadIdx.x & 63;
  if (wave >= N_NODES) return;
  int start = offsets[wave];
  int n = counts[wave];
  float2 acc = make_float2(0.f, 0.f);
  for (int base = 0; base < n; base += 64) {
    int m = n - base;
    if (m > 64) m = 64;
    int c = 0;
    float v = 0.f;
    if (lane < m) {
      int2 e = edata[start + base + lane];
      c = e.x;
      v = __builtin_bit_cast(float, e.y);
    }
    for (int j = 0; j < m; ++j) {
      int cj = __shfl(c, j, 64);
      float vj = __shfl(v, j, 64);
      unsigned t = *(const unsigned*)(tb + (size_t)cj * F_OUT + lane * 2);
      acc.x = fmaf(vj, __builtin_bit_cast(float, t << 16), acc.x);
      acc.y = fmaf(vj, __builtin_bit_cast(float, t & 0xffff0000u), acc.y);
    }
  }
  ((float2*)out)[(size_t)wave * 64 + lane] = acc;
}

extern "C" void kernel_launch(void* const* d_in, const int* in_sizes, int n_in,
                              void* d_out, int out_size, void* d_ws, size_t ws_size,
                              hipStream_t stream) {
  const float* x    = (const float*)d_in[0];
  const int*   rows = (const int*)d_in[1];
  const int*   cols = (const int*)d_in[2];
  const float* vals = (const float*)d_in[3];
  const float* W    = (const float*)d_in[4];
  const float* b    = (const float*)d_in[5];
  float* out = (float*)d_out;
  const int E = in_sizes[1];

  // ws layout: transformed_bf16 | counts | offsets | cursor | blockSums | edata
  unsigned short* tb = (unsigned short*)d_ws;
  int* counts    = (int*)(tb + (size_t)N_NODES * F_OUT);
  int* offsets   = counts + N_NODES;
  int* cursor    = offsets + N_NODES;
  int* blockSums = cursor + N_NODES;
  int2* edata    = (int2*)(blockSums + 512);  // byte offset %8 == 0

  hipMemsetAsync(counts, 0, N_NODES * sizeof(int), stream);

  gemm_kernel<<<(N_NODES + 127) / 128, 256, 0, stream>>>(x, W, b, tb);
  hist_kernel<<<(E + 255) / 256, 256, 0, stream>>>(rows, counts, E);
  scan1_kernel<<<SCAN_BLOCKS, 256, 0, stream>>>(counts, offsets, blockSums);
  scan2_kernel<<<1, 512, 0, stream>>>(blockSums, SCAN_BLOCKS);
  scan3_kernel<<<SCAN_BLOCKS, 256, 0, stream>>>(offsets, blockSums, cursor);
  fill_kernel<<<(E + 255) / 256, 256, 0, stream>>>(rows, cols, vals, cursor, edata, E);
  spmm_kernel<<<(N_NODES + 3) / 4, 256, 0, stream>>>(tb, edata, offsets, counts, out);
}

// Round 3
// 442.334 us; speedup vs baseline: 1.4505x; 1.1359x over previous
//
#include <hip/hip_runtime.h>

#define N_NODES 100000
#define F_IN 256
#define F_OUT 128
#define NB 1563      // ceil(N_NODES/64) buckets of 64 rows
#define BCAP 1536    // mean 1024, sigma 32 -> +16 sigma headroom

typedef __attribute__((ext_vector_type(8))) short bf16x8;
typedef __attribute__((ext_vector_type(4))) float f32x4;

__device__ inline unsigned short f2bf(float f) {  // RNE fp32->bf16
  unsigned u = __builtin_bit_cast(unsigned, f);
  u += 0x7fffu + ((u >> 16) & 1u);
  return (unsigned short)(u >> 16);
}

// ---------------- GEMM (bf16 MFMA): transformed[n][o] = x[n][:]·W[o][:] + b[o]
__global__ __launch_bounds__(256) void gemm_kernel(
    const float* __restrict__ x, const float* __restrict__ W,
    const float* __restrict__ b, unsigned short* __restrict__ tout) {
  __shared__ unsigned short As[128][72];
  __shared__ unsigned short Bs[128][72];
  const int tid = threadIdx.x;
  const int wave = tid >> 6, lane = tid & 63;
  const int quad = lane >> 4, l16 = lane & 15;
  const int mw = (wave >> 1) * 64, nw = (wave & 1) * 64;
  const int blockM = blockIdx.x * 128;

  f32x4 acc[4][4];
#pragma unroll
  for (int i = 0; i < 4; ++i)
#pragma unroll
    for (int j = 0; j < 4; ++j) acc[i][j] = (f32x4){0.f, 0.f, 0.f, 0.f};

  const int row_s = tid >> 4;
  const int c4 = tid & 15;

  for (int kb = 0; kb < F_IN; kb += 64) {
#pragma unroll
    for (int i = 0; i < 8; ++i) {
      int r = row_s + i * 16;
      int node = blockM + r;
      float4 v = make_float4(0.f, 0.f, 0.f, 0.f);
      if (node < N_NODES) v = *(const float4*)(x + (size_t)node * F_IN + kb + c4 * 4);
      unsigned short* p = &As[r][c4 * 4];
      p[0] = f2bf(v.x); p[1] = f2bf(v.y); p[2] = f2bf(v.z); p[3] = f2bf(v.w);
    }
#pragma unroll
    for (int i = 0; i < 8; ++i) {
      int r = row_s + i * 16;
      float4 v = *(const float4*)(W + (size_t)r * F_IN + kb + c4 * 4);
      unsigned short* p = &Bs[r][c4 * 4];
      p[0] = f2bf(v.x); p[1] = f2bf(v.y); p[2] = f2bf(v.z); p[3] = f2bf(v.w);
    }
    __syncthreads();
#pragma unroll
    for (int ks = 0; ks < 2; ++ks) {
      bf16x8 a[4], bb[4];
#pragma unroll
      for (int t = 0; t < 4; ++t)
        a[t] = *(const bf16x8*)&As[mw + t * 16 + l16][ks * 32 + quad * 8];
#pragma unroll
      for (int t = 0; t < 4; ++t)
        bb[t] = *(const bf16x8*)&Bs[nw + t * 16 + l16][ks * 32 + quad * 8];
#pragma unroll
      for (int i = 0; i < 4; ++i)
#pragma unroll
        for (int j = 0; j < 4; ++j)
          acc[i][j] = __builtin_amdgcn_mfma_f32_16x16x32_bf16(a[i], bb[j], acc[i][j], 0, 0, 0);
    }
    __syncthreads();
  }
#pragma unroll
  for (int i = 0; i < 4; ++i) {
#pragma unroll
    for (int j = 0; j < 4; ++j) {
      int o = nw + j * 16 + l16;
      float bias = b[o];
#pragma unroll
      for (int r = 0; r < 4; ++r) {
        int node = blockM + mw + i * 16 + quad * 4 + r;
        if (node < N_NODES)
          tout[(size_t)node * F_OUT + o] = f2bf(acc[i][j][r] + bias);
      }
    }
  }
}

// ---------------- Phase A: bucket-append edges -----------------------------
// staged record: (rlocal<<17 | col, val_bits). cursor stride 16 ints (1 line).
__global__ void phaseA_kernel(const int* __restrict__ rows, const int* __restrict__ cols,
                              const float* __restrict__ vals, int* __restrict__ cursor,
                              int2* __restrict__ staging, int E) {
  int i = blockIdx.x * blockDim.x + threadIdx.x;
  if (i < E) {
    int r = rows[i];
    int bkt = r >> 6;
    int p = atomicAdd(&cursor[bkt * 16], 1);
    if (p < BCAP)
      staging[(size_t)bkt * BCAP + p] =
          make_int2(((r & 63) << 17) | cols[i], __float_as_int(vals[i]));
  }
}

// ---------------- exclusive scan of NB bucket counts (single block) --------
__global__ __launch_bounds__(1024) void scan_buckets_kernel(
    const int* __restrict__ cursor, int* __restrict__ bucketOff) {
  __shared__ int s[1024];
  __shared__ int carry;
  if (threadIdx.x == 0) carry = 0;
  __syncthreads();
  for (int chunk = 0; chunk < NB; chunk += 1024) {
    int i = chunk + threadIdx.x;
    int v = (i < NB) ? min(cursor[i * 16], BCAP) : 0;
    s[threadIdx.x] = v;
    __syncthreads();
    for (int off = 1; off < 1024; off <<= 1) {
      int t = (threadIdx.x >= off) ? s[threadIdx.x - off] : 0;
      __syncthreads();
      s[threadIdx.x] += t;
      __syncthreads();
    }
    if (i < NB) bucketOff[i] = carry + s[threadIdx.x] - v;
    __syncthreads();
    if (threadIdx.x == 1023) carry += s[1023];
    __syncthreads();
  }
}

// ---------------- Phase B: within-bucket sort -> final CSR -----------------
__global__ __launch_bounds__(256) void phaseB_kernel(
    const int2* __restrict__ staging, const int* __restrict__ cursor,
    const int* __restrict__ bucketOff, int2* __restrict__ edata,
    int* __restrict__ rowOff, int* __restrict__ rowCnt) {
  int b = blockIdx.x;
  int cnt = min(cursor[b * 16], BCAP);
  int base = bucketOff[b];
  __shared__ int rc[64];   // histogram, then reused as cursor
  __shared__ int ro[64];   // exclusive offsets
  if (threadIdx.x < 64) rc[threadIdx.x] = 0;
  __syncthreads();
  for (int i = threadIdx.x; i < cnt; i += 256)
    atomicAdd(&rc[staging[(size_t)b * BCAP + i].x >> 17], 1);
  __syncthreads();
  if (threadIdx.x < 64) {
    int v = rc[threadIdx.x];
    int sum = v;
#pragma unroll
    for (int off = 1; off < 64; off <<= 1) {
      int t = __shfl_up(sum, off, 64);
      if ((threadIdx.x & 63) >= off) sum += t;
    }
    ro[threadIdx.x] = sum - v;
    rc[threadIdx.x] = 0;
    int row = b * 64 + threadIdx.x;
    if (row < N_NODES) {
      rowOff[row] = base + sum - v;
      rowCnt[row] = v;
    }
  }
  __syncthreads();
  for (int i = threadIdx.x; i < cnt; i += 256) {
    int2 e = staging[(size_t)b * BCAP + i];
    int rl = e.x >> 17;
    int slot = atomicAdd(&rc[rl], 1);
    edata[base + ro[rl] + slot] = make_int2(e.x & 0x1FFFF, e.y);
  }
}

// ---------------- SpMM: one wave per row, bf16 gathers ---------------------
__global__ __launch_bounds__(256) void spmm_kernel(
    const unsigned short* __restrict__ tb, const int2* __restrict__ edata,
    const int* __restrict__ rowOff, const int* __restrict__ rowCnt,
    float* __restrict__ out) {
  int wave = (blockIdx.x * 256 + threadIdx.x) >> 6;
  int lane = threadIdx.x & 63;
  if (wave >= N_NODES) return;
  int start = rowOff[wave];
  int n = rowCnt[wave];
  float2 acc = make_float2(0.f, 0.f);
  for (int base = 0; base < n; base += 64) {
    int m = n - base;
    if (m > 64) m = 64;
    int c = 0;
    float v = 0.f;
    if (lane < m) {
      int2 e = edata[start + base + lane];
      c = e.x;
      v = __builtin_bit_cast(float, e.y);
    }
    for (int j = 0; j < m; ++j) {
      int cj = __shfl(c, j, 64);
      float vj = __shfl(v, j, 64);
      unsigned t = *(const unsigned*)(tb + (size_t)cj * F_OUT + lane * 2);
      acc.x = fmaf(vj, __builtin_bit_cast(float, t << 16), acc.x);
      acc.y = fmaf(vj, __builtin_bit_cast(float, t & 0xffff0000u), acc.y);
    }
  }
  ((float2*)out)[(size_t)wave * 64 + lane] = acc;
}

extern "C" void kernel_launch(void* const* d_in, const int* in_sizes, int n_in,
                              void* d_out, int out_size, void* d_ws, size_t ws_size,
                              hipStream_t stream) {
  const float* x    = (const float*)d_in[0];
  const int*   rows = (const int*)d_in[1];
  const int*   cols = (const int*)d_in[2];
  const float* vals = (const float*)d_in[3];
  const float* W    = (const float*)d_in[4];
  const float* b    = (const float*)d_in[5];
  float* out = (float*)d_out;
  const int E = in_sizes[1];

  // ws layout: region0 = staging (19.2MB) ALIASED with tb (25.6MB; gemm runs
  // after phaseB) | edata 12.8MB | cursor NB*16 | bucketOff | rowOff | rowCnt
  unsigned short* tb = (unsigned short*)d_ws;
  int2* staging  = (int2*)d_ws;
  int2* edata    = (int2*)(tb + (size_t)N_NODES * F_OUT);
  int* cursor    = (int*)(edata + 1600000);
  int* bucketOff = cursor + NB * 16;
  int* rowOff    = bucketOff + ((NB + 1) & ~1);
  int* rowCnt    = rowOff + N_NODES;

  hipMemsetAsync(cursor, 0, NB * 16 * sizeof(int), stream);

  phaseA_kernel<<<(E + 255) / 256, 256, 0, stream>>>(rows, cols, vals, cursor, staging, E);
  scan_buckets_kernel<<<1, 1024, 0, stream>>>(cursor, bucketOff);
  phaseB_kernel<<<NB, 256, 0, stream>>>(staging, cursor, bucketOff, edata, rowOff, rowCnt);
  gemm_kernel<<<(N_NODES + 127) / 128, 256, 0, stream>>>(x, W, b, tb);  // overwrites staging
  spmm_kernel<<<(N_NODES + 3) / 4, 256, 0, stream>>>(tb, edata, rowOff, rowCnt, out);
}

// Round 4
// 412.412 us; speedup vs baseline: 1.5558x; 1.0726x over previous
//
#include <hip/hip_runtime.h>

#define N_NODES 100000
#define F_IN 256
#define F_OUT 128
#define NB 1563      // ceil(N_NODES/64) buckets of 64 rows
#define SUBCAP 256   // per (bucket, xcd): mean 128, +11 sigma headroom

typedef __attribute__((ext_vector_type(8))) short bf16x8;
typedef __attribute__((ext_vector_type(4))) float f32x4;

__device__ inline unsigned short f2bf(float f) {  // RNE fp32->bf16
  unsigned u = __builtin_bit_cast(unsigned, f);
  u += 0x7fffu + ((u >> 16) & 1u);
  return (unsigned short)(u >> 16);
}

// physical XCD id (gfx950: HW_REG_XCC_ID = hwreg 20). Correctness does NOT
// depend on this value -- it only selects a staging sub-region for locality.
__device__ inline int xcd_id() {
  return __builtin_amdgcn_s_getreg((3 << 11) | (0 << 6) | 20) & 7;
}

// ---------------- GEMM (bf16 MFMA): transformed[n][o] = x[n][:]·W[o][:] + b[o]
__global__ __launch_bounds__(256) void gemm_kernel(
    const float* __restrict__ x, const float* __restrict__ W,
    const float* __restrict__ b, unsigned short* __restrict__ tout) {
  __shared__ unsigned short As[128][72];
  __shared__ unsigned short Bs[128][72];
  const int tid = threadIdx.x;
  const int wave = tid >> 6, lane = tid & 63;
  const int quad = lane >> 4, l16 = lane & 15;
  const int mw = (wave >> 1) * 64, nw = (wave & 1) * 64;
  const int blockM = blockIdx.x * 128;

  f32x4 acc[4][4];
#pragma unroll
  for (int i = 0; i < 4; ++i)
#pragma unroll
    for (int j = 0; j < 4; ++j) acc[i][j] = (f32x4){0.f, 0.f, 0.f, 0.f};

  const int row_s = tid >> 4;
  const int c4 = tid & 15;

  for (int kb = 0; kb < F_IN; kb += 64) {
#pragma unroll
    for (int i = 0; i < 8; ++i) {
      int r = row_s + i * 16;
      int node = blockM + r;
      float4 v = make_float4(0.f, 0.f, 0.f, 0.f);
      if (node < N_NODES) v = *(const float4*)(x + (size_t)node * F_IN + kb + c4 * 4);
      unsigned short* p = &As[r][c4 * 4];
      p[0] = f2bf(v.x); p[1] = f2bf(v.y); p[2] = f2bf(v.z); p[3] = f2bf(v.w);
    }
#pragma unroll
    for (int i = 0; i < 8; ++i) {
      int r = row_s + i * 16;
      float4 v = *(const float4*)(W + (size_t)r * F_IN + kb + c4 * 4);
      unsigned short* p = &Bs[r][c4 * 4];
      p[0] = f2bf(v.x); p[1] = f2bf(v.y); p[2] = f2bf(v.z); p[3] = f2bf(v.w);
    }
    __syncthreads();
#pragma unroll
    for (int ks = 0; ks < 2; ++ks) {
      bf16x8 a[4], bb[4];
#pragma unroll
      for (int t = 0; t < 4; ++t)
        a[t] = *(const bf16x8*)&As[mw + t * 16 + l16][ks * 32 + quad * 8];
#pragma unroll
      for (int t = 0; t < 4; ++t)
        bb[t] = *(const bf16x8*)&Bs[nw + t * 16 + l16][ks * 32 + quad * 8];
#pragma unroll
      for (int i = 0; i < 4; ++i)
#pragma unroll
        for (int j = 0; j < 4; ++j)
          acc[i][j] = __builtin_amdgcn_mfma_f32_16x16x32_bf16(a[i], bb[j], acc[i][j], 0, 0, 0);
    }
    __syncthreads();
  }
#pragma unroll
  for (int i = 0; i < 4; ++i) {
#pragma unroll
    for (int j = 0; j < 4; ++j) {
      int o = nw + j * 16 + l16;
      float bias = b[o];
#pragma unroll
      for (int r = 0; r < 4; ++r) {
        int node = blockM + mw + i * 16 + quad * 4 + r;
        if (node < N_NODES)
          tout[(size_t)node * F_OUT + o] = f2bf(acc[i][j][r] + bias);
      }
    }
  }
}

// ---------------- Phase A: XCD-local bucket append -------------------------
// record: (rlocal<<17 | col, val_bits). counter per (bucket,xcd), 64B strided.
__global__ void phaseA_kernel(const int* __restrict__ rows, const int* __restrict__ cols,
                              const float* __restrict__ vals, int* __restrict__ cursor,
                              int2* __restrict__ staging, int E) {
  int i = blockIdx.x * blockDim.x + threadIdx.x;
  int xc = xcd_id();
  if (i < E) {
    int r = rows[i];
    int bkt = r >> 6;
    int p = atomicAdd(&cursor[(bkt * 8 + xc) * 16], 1);
    if (p < SUBCAP)
      staging[((size_t)bkt * 8 + xc) * SUBCAP + p] =
          make_int2(((r & 63) << 17) | cols[i], __float_as_int(vals[i]));
  }
}

// ---------------- exclusive scan of NB bucket totals (single block) --------
__global__ __launch_bounds__(1024) void scan_buckets_kernel(
    const int* __restrict__ cursor, int* __restrict__ bucketOff) {
  __shared__ int s[1024];
  __shared__ int carry;
  if (threadIdx.x == 0) carry = 0;
  __syncthreads();
  for (int chunk = 0; chunk < NB; chunk += 1024) {
    int i = chunk + threadIdx.x;
    int v = 0;
    if (i < NB) {
#pragma unroll
      for (int s8 = 0; s8 < 8; ++s8) v += min(cursor[(i * 8 + s8) * 16], SUBCAP);
    }
    s[threadIdx.x] = v;
    __syncthreads();
    for (int off = 1; off < 1024; off <<= 1) {
      int t = (threadIdx.x >= off) ? s[threadIdx.x - off] : 0;
      __syncthreads();
      s[threadIdx.x] += t;
      __syncthreads();
    }
    if (i < NB) bucketOff[i] = carry + s[threadIdx.x] - v;
    __syncthreads();
    if (threadIdx.x == 1023) carry += s[1023];
    __syncthreads();
  }
}

// ---------------- Phase B: merge 8 sub-lists -> final CSR ------------------
__global__ __launch_bounds__(256) void phaseB_kernel(
    const int2* __restrict__ staging, const int* __restrict__ cursor,
    const int* __restrict__ bucketOff, int2* __restrict__ edata,
    int* __restrict__ rowOff, int* __restrict__ rowCnt) {
  int b = blockIdx.x;
  int base = bucketOff[b];
  __shared__ int rc[64];
  __shared__ int ro[64];
  __shared__ int scnt[8];
  if (threadIdx.x < 8) scnt[threadIdx.x] = min(cursor[(b * 8 + threadIdx.x) * 16], SUBCAP);
  if (threadIdx.x < 64) rc[threadIdx.x] = 0;
  __syncthreads();
#pragma unroll
  for (int s = 0; s < 8; ++s) {
    int cs = scnt[s];
    const int2* sp = staging + ((size_t)b * 8 + s) * SUBCAP;
    for (int i = threadIdx.x; i < cs; i += 256)
      atomicAdd(&rc[sp[i].x >> 17], 1);
  }
  __syncthreads();
  if (threadIdx.x < 64) {
    int v = rc[threadIdx.x];
    int sum = v;
#pragma unroll
    for (int off = 1; off < 64; off <<= 1) {
      int t = __shfl_up(sum, off, 64);
      if ((threadIdx.x & 63) >= off) sum += t;
    }
    ro[threadIdx.x] = sum - v;
    rc[threadIdx.x] = 0;
    int row = b * 64 + threadIdx.x;
    if (row < N_NODES) {
      rowOff[row] = base + sum - v;
      rowCnt[row] = v;
    }
  }
  __syncthreads();
#pragma unroll
  for (int s = 0; s < 8; ++s) {
    int cs = scnt[s];
    const int2* sp = staging + ((size_t)b * 8 + s) * SUBCAP;
    for (int i = threadIdx.x; i < cs; i += 256) {
      int2 e = sp[i];
      int rl = e.x >> 17;
      int slot = atomicAdd(&rc[rl], 1);
      edata[base + ro[rl] + slot] = make_int2(e.x & 0x1FFFF, e.y);
    }
  }
}

// ---------------- SpMM: one wave per row, bf16 gathers ---------------------
__global__ __launch_bounds__(256) void spmm_kernel(
    const unsigned short* __restrict__ tb, const int2* __restrict__ edata,
    const int* __restrict__ rowOff, const int* __restrict__ rowCnt,
    float* __restrict__ out) {
  int wave = (blockIdx.x * 256 + threadIdx.x) >> 6;
  int lane = threadIdx.x & 63;
  if (wave >= N_NODES) return;
  int start = rowOff[wave];
  int n = rowCnt[wave];
  float2 acc = make_float2(0.f, 0.f);
  for (int base = 0; base < n; base += 64) {
    int m = n - base;
    if (m > 64) m = 64;
    int c = 0;
    float v = 0.f;
    if (lane < m) {
      int2 e = edata[start + base + lane];
      c = e.x;
      v = __builtin_bit_cast(float, e.y);
    }
    for (int j = 0; j < m; ++j) {
      int cj = __shfl(c, j, 64);
      float vj = __shfl(v, j, 64);
      unsigned t = *(const unsigned*)(tb + (size_t)cj * F_OUT + lane * 2);
      acc.x = fmaf(vj, __builtin_bit_cast(float, t << 16), acc.x);
      acc.y = fmaf(vj, __builtin_bit_cast(float, t & 0xffff0000u), acc.y);
    }
  }
  ((float2*)out)[(size_t)wave * 64 + lane] = acc;
}

extern "C" void kernel_launch(void* const* d_in, const int* in_sizes, int n_in,
                              void* d_out, int out_size, void* d_ws, size_t ws_size,
                              hipStream_t stream) {
  const float* x    = (const float*)d_in[0];
  const int*   rows = (const int*)d_in[1];
  const int*   cols = (const int*)d_in[2];
  const float* vals = (const float*)d_in[3];
  const float* W    = (const float*)d_in[4];
  const float* b    = (const float*)d_in[5];
  float* out = (float*)d_out;
  const int E = in_sizes[1];

  // ws layout: region0 = staging (NB*8*SUBCAP*8 = 25.61MB) ALIASED with
  // tb (25.6MB; gemm runs after phaseB) | edata | cursor | bucketOff | rowOff | rowCnt
  const size_t region0 = (size_t)NB * 8 * SUBCAP * sizeof(int2);  // >= tb bytes
  unsigned short* tb = (unsigned short*)d_ws;
  int2* staging  = (int2*)d_ws;
  int2* edata    = (int2*)((char*)d_ws + region0);
  int* cursor    = (int*)(edata + E);
  int* bucketOff = cursor + NB * 8 * 16;
  int* rowOff    = bucketOff + ((NB + 1) & ~1);
  int* rowCnt    = rowOff + N_NODES;

  hipMemsetAsync(cursor, 0, (size_t)NB * 8 * 16 * sizeof(int), stream);

  phaseA_kernel<<<(E + 255) / 256, 256, 0, stream>>>(rows, cols, vals, cursor, staging, E);
  scan_buckets_kernel<<<1, 1024, 0, stream>>>(cursor, bucketOff);
  phaseB_kernel<<<NB, 256, 0, stream>>>(staging, cursor, bucketOff, edata, rowOff, rowCnt);
  gemm_kernel<<<(N_NODES + 127) / 128, 256, 0, stream>>>(x, W, b, tb);  // overwrites staging
  spmm_kernel<<<(N_NODES + 3) / 4, 256, 0, stream>>>(tb, edata, rowOff, rowCnt, out);
}

// Round 5
// 365.940 us; speedup vs baseline: 1.7533x; 1.1270x over previous
//
#include <hip/hip_runtime.h>

#define N_NODES 100000
#define F_IN 256
#define F_OUT 128
#define NB 1563      // ceil(N_NODES/64) buckets of 64 rows
#define SUBCAP 256   // per (bucket, xcd): mean 128, +11 sigma headroom

typedef __attribute__((ext_vector_type(8))) short bf16x8;
typedef __attribute__((ext_vector_type(4))) float f32x4;

__device__ inline unsigned short f2bf(float f) {  // RNE fp32->bf16
  unsigned u = __builtin_bit_cast(unsigned, f);
  u += 0x7fffu + ((u >> 16) & 1u);
  return (unsigned short)(u >> 16);
}

// physical XCD id (gfx950: HW_REG_XCC_ID = hwreg 20). Correctness does NOT
// depend on this value -- it only selects a staging sub-region for locality.
__device__ inline int xcd_id() {
  return __builtin_amdgcn_s_getreg((3 << 11) | (0 << 6) | 20) & 7;
}

// ---------------- GEMM (bf16 MFMA): transformed[n][o] = x[n][:]·W[o][:] + b[o]
__global__ __launch_bounds__(256) void gemm_kernel(
    const float* __restrict__ x, const float* __restrict__ W,
    const float* __restrict__ b, unsigned short* __restrict__ tout) {
  __shared__ unsigned short As[128][72];
  __shared__ unsigned short Bs[128][72];
  const int tid = threadIdx.x;
  const int wave = tid >> 6, lane = tid & 63;
  const int quad = lane >> 4, l16 = lane & 15;
  const int mw = (wave >> 1) * 64, nw = (wave & 1) * 64;
  const int blockM = blockIdx.x * 128;

  f32x4 acc[4][4];
#pragma unroll
  for (int i = 0; i < 4; ++i)
#pragma unroll
    for (int j = 0; j < 4; ++j) acc[i][j] = (f32x4){0.f, 0.f, 0.f, 0.f};

  const int row_s = tid >> 4;
  const int c4 = tid & 15;

  for (int kb = 0; kb < F_IN; kb += 64) {
#pragma unroll
    for (int i = 0; i < 8; ++i) {
      int r = row_s + i * 16;
      int node = blockM + r;
      float4 v = make_float4(0.f, 0.f, 0.f, 0.f);
      if (node < N_NODES) v = *(const float4*)(x + (size_t)node * F_IN + kb + c4 * 4);
      unsigned short* p = &As[r][c4 * 4];
      p[0] = f2bf(v.x); p[1] = f2bf(v.y); p[2] = f2bf(v.z); p[3] = f2bf(v.w);
    }
#pragma unroll
    for (int i = 0; i < 8; ++i) {
      int r = row_s + i * 16;
      float4 v = *(const float4*)(W + (size_t)r * F_IN + kb + c4 * 4);
      unsigned short* p = &Bs[r][c4 * 4];
      p[0] = f2bf(v.x); p[1] = f2bf(v.y); p[2] = f2bf(v.z); p[3] = f2bf(v.w);
    }
    __syncthreads();
#pragma unroll
    for (int ks = 0; ks < 2; ++ks) {
      bf16x8 a[4], bb[4];
#pragma unroll
      for (int t = 0; t < 4; ++t)
        a[t] = *(const bf16x8*)&As[mw + t * 16 + l16][ks * 32 + quad * 8];
#pragma unroll
      for (int t = 0; t < 4; ++t)
        bb[t] = *(const bf16x8*)&Bs[nw + t * 16 + l16][ks * 32 + quad * 8];
#pragma unroll
      for (int i = 0; i < 4; ++i)
#pragma unroll
        for (int j = 0; j < 4; ++j)
          acc[i][j] = __builtin_amdgcn_mfma_f32_16x16x32_bf16(a[i], bb[j], acc[i][j], 0, 0, 0);
    }
    __syncthreads();
  }
#pragma unroll
  for (int i = 0; i < 4; ++i) {
#pragma unroll
    for (int j = 0; j < 4; ++j) {
      int o = nw + j * 16 + l16;
      float bias = b[o];
#pragma unroll
      for (int r = 0; r < 4; ++r) {
        int node = blockM + mw + i * 16 + quad * 4 + r;
        if (node < N_NODES)
          tout[(size_t)node * F_OUT + o] = f2bf(acc[i][j][r] + bias);
      }
    }
  }
}

// ---------------- Phase A: XCD-local bucket append -------------------------
__global__ void phaseA_kernel(const int* __restrict__ rows, const int* __restrict__ cols,
                              const float* __restrict__ vals, int* __restrict__ cursor,
                              int2* __restrict__ staging, int E) {
  int i = blockIdx.x * blockDim.x + threadIdx.x;
  int xc = xcd_id();
  if (i < E) {
    int r = rows[i];
    int bkt = r >> 6;
    int p = atomicAdd(&cursor[(bkt * 8 + xc) * 16], 1);
    if (p < SUBCAP)
      staging[((size_t)bkt * 8 + xc) * SUBCAP + p] =
          make_int2(((r & 63) << 17) | cols[i], __float_as_int(vals[i]));
  }
}

// ---------------- exclusive scan of NB bucket totals (single block) --------
__global__ __launch_bounds__(1024) void scan_buckets_kernel(
    const int* __restrict__ cursor, int* __restrict__ bucketOff) {
  __shared__ int s[1024];
  __shared__ int carry;
  if (threadIdx.x == 0) carry = 0;
  __syncthreads();
  for (int chunk = 0; chunk < NB; chunk += 1024) {
    int i = chunk + threadIdx.x;
    int v = 0;
    if (i < NB) {
#pragma unroll
      for (int s8 = 0; s8 < 8; ++s8) v += min(cursor[(i * 8 + s8) * 16], SUBCAP);
    }
    s[threadIdx.x] = v;
    __syncthreads();
    for (int off = 1; off < 1024; off <<= 1) {
      int t = (threadIdx.x >= off) ? s[threadIdx.x - off] : 0;
      __syncthreads();
      s[threadIdx.x] += t;
      __syncthreads();
    }
    if (i < NB) bucketOff[i] = carry + s[threadIdx.x] - v;
    __syncthreads();
    if (threadIdx.x == 1023) carry += s[1023];
    __syncthreads();
  }
}

// ---------------- Phase B: merge 8 sub-lists -> final CSR ------------------
__global__ __launch_bounds__(256) void phaseB_kernel(
    const int2* __restrict__ staging, const int* __restrict__ cursor,
    const int* __restrict__ bucketOff, int2* __restrict__ edata,
    int* __restrict__ rowOff, int* __restrict__ rowCnt) {
  int b = blockIdx.x;
  int base = bucketOff[b];
  __shared__ int rc[64];
  __shared__ int ro[64];
  __shared__ int scnt[8];
  if (threadIdx.x < 8) scnt[threadIdx.x] = min(cursor[(b * 8 + threadIdx.x) * 16], SUBCAP);
  if (threadIdx.x < 64) rc[threadIdx.x] = 0;
  __syncthreads();
#pragma unroll
  for (int s = 0; s < 8; ++s) {
    int cs = scnt[s];
    const int2* sp = staging + ((size_t)b * 8 + s) * SUBCAP;
    for (int i = threadIdx.x; i < cs; i += 256)
      atomicAdd(&rc[sp[i].x >> 17], 1);
  }
  __syncthreads();
  if (threadIdx.x < 64) {
    int v = rc[threadIdx.x];
    int sum = v;
#pragma unroll
    for (int off = 1; off < 64; off <<= 1) {
      int t = __shfl_up(sum, off, 64);
      if ((threadIdx.x & 63) >= off) sum += t;
    }
    ro[threadIdx.x] = sum - v;
    rc[threadIdx.x] = 0;
    int row = b * 64 + threadIdx.x;
    if (row < N_NODES) {
      rowOff[row] = base + sum - v;
      rowCnt[row] = v;
    }
  }
  __syncthreads();
#pragma unroll
  for (int s = 0; s < 8; ++s) {
    int cs = scnt[s];
    const int2* sp = staging + ((size_t)b * 8 + s) * SUBCAP;
    for (int i = threadIdx.x; i < cs; i += 256) {
      int2 e = sp[i];
      int rl = e.x >> 17;
      int slot = atomicAdd(&rc[rl], 1);
      edata[base + ro[rl] + slot] = make_int2(e.x & 0x1FFFF, e.y);
    }
  }
}

// ---------------- SpMM: one wave per row, 8-deep batched gathers -----------
__global__ __launch_bounds__(256) void spmm_kernel(
    const unsigned short* __restrict__ tb, const int2* __restrict__ edata,
    const int* __restrict__ rowOff, const int* __restrict__ rowCnt,
    float* __restrict__ out) {
  int wave = (blockIdx.x * 256 + threadIdx.x) >> 6;
  int lane = threadIdx.x & 63;
  if (wave >= N_NODES) return;
  int start = rowOff[wave];
  int n = rowCnt[wave];
  float2 acc = make_float2(0.f, 0.f);
  for (int base = 0; base < n; base += 64) {
    int m = n - base;
    if (m > 64) m = 64;
    int c = 0;
    float v = 0.f;
    if (lane < m) {
      int2 e = edata[start + base + lane];
      c = e.x;
      v = __builtin_bit_cast(float, e.y);
    }
    // groups of 8: 8 independent loads in flight per wave. Tail lanes
    // (j>=m) hold c=0,v=0 -> safe load of hot row 0, FMA contributes 0.
    for (int j0 = 0; j0 < m; j0 += 8) {
      unsigned t[8];
      float vj[8];
#pragma unroll
      for (int jj = 0; jj < 8; ++jj) {
        int cj = __shfl(c, j0 + jj, 64);
        vj[jj] = __shfl(v, j0 + jj, 64);
        t[jj] = *(const unsigned*)(tb + (size_t)cj * F_OUT + lane * 2);
      }
#pragma unroll
      for (int jj = 0; jj < 8; ++jj) {
        acc.x = fmaf(vj[jj], __builtin_bit_cast(float, t[jj] << 16), acc.x);
        acc.y = fmaf(vj[jj], __builtin_bit_cast(float, t[jj] & 0xffff0000u), acc.y);
      }
    }
  }
  ((float2*)out)[(size_t)wave * 64 + lane] = acc;
}

extern "C" void kernel_launch(void* const* d_in, const int* in_sizes, int n_in,
                              void* d_out, int out_size, void* d_ws, size_t ws_size,
                              hipStream_t stream) {
  const float* x    = (const float*)d_in[0];
  const int*   rows = (const int*)d_in[1];
  const int*   cols = (const int*)d_in[2];
  const float* vals = (const float*)d_in[3];
  const float* W    = (const float*)d_in[4];
  const float* b    = (const float*)d_in[5];
  float* out = (float*)d_out;
  const int E = in_sizes[1];

  // ws layout: region0 = staging (NB*8*SUBCAP*8 = 25.61MB) ALIASED with
  // tb (25.6MB; gemm runs after phaseB) | edata | cursor | bucketOff | rowOff | rowCnt
  const size_t region0 = (size_t)NB * 8 * SUBCAP * sizeof(int2);  // >= tb bytes
  unsigned short* tb = (unsigned short*)d_ws;
  int2* staging  = (int2*)d_ws;
  int2* edata    = (int2*)((char*)d_ws + region0);
  int* cursor    = (int*)(edata + E);
  int* bucketOff = cursor + NB * 8 * 16;
  int* rowOff    = bucketOff + ((NB + 1) & ~1);
  int* rowCnt    = rowOff + N_NODES;

  hipMemsetAsync(cursor, 0, (size_t)NB * 8 * 16 * sizeof(int), stream);

  phaseA_kernel<<<(E + 255) / 256, 256, 0, stream>>>(rows, cols, vals, cursor, staging, E);
  scan_buckets_kernel<<<1, 1024, 0, stream>>>(cursor, bucketOff);
  phaseB_kernel<<<NB, 256, 0, stream>>>(staging, cursor, bucketOff, edata, rowOff, rowCnt);
  gemm_kernel<<<(N_NODES + 127) / 128, 256, 0, stream>>>(x, W, b, tb);  // overwrites staging
  spmm_kernel<<<(N_NODES + 3) / 4, 256, 0, stream>>>(tb, edata, rowOff, rowCnt, out);
}